// Round 1
// baseline (704.864 us; speedup 1.0000x reference)
//
#include <hip/hip_runtime.h>
#include <hip/hip_bf16.h>
#include <stdint.h>

// LongcatMoe: T=4096 tokens, H=1024, I=512, E=64 routed + 16 zero experts,
// top-2 sigmoid gating, CAP=320, scale=1.5.
// Pipeline: memset(cnt) -> router(fp32) -> gate/up bf16 MFMA GEMM (+silu*up)
//           -> down bf16 MFMA GEMM (scatter to y2[t,k]) -> combine.
// Expert weights (402 MB fp32) are streamed exactly once => memory-bound.

#define T_TOK 4096
#define HDIM  1024
#define IDIM  512
#define NE    64
#define NEZ   80
#define CAPE  320
#define SCALEF 1.5f

#define LDR 72  // LDS row pitch in bf16 elems (64 + 8 pad), 144 B (16B-aligned)

typedef __attribute__((ext_vector_type(8))) short bf16x8;
typedef __attribute__((ext_vector_type(4))) float floatx4;

static __device__ __forceinline__ unsigned short f2bf(float f) {
    unsigned int x = __float_as_uint(f);
    x += 0x7fffu + ((x >> 16) & 1u);   // RNE
    return (unsigned short)(x >> 16);
}
static __device__ __forceinline__ float bf2f(unsigned short u) {
    return __uint_as_float(((unsigned int)u) << 16);
}

// ---------------- Router: fp32 logits, sigmoid, top-2, dispatch ----------------
// block = 256 (4 waves), each wave handles 4 tokens; grid = 4096/16 = 256.
__global__ __launch_bounds__(256) void router_kernel(
    const float* __restrict__ hidden, const float* __restrict__ rw,
    const float* __restrict__ bias, int* __restrict__ cnt,
    int* __restrict__ slot_tok, float* __restrict__ w_routed,
    float* __restrict__ zc)
{
    __shared__ float sc[16][NEZ];
    const int tid = threadIdx.x;
    const int w = tid >> 6, lane = tid & 63;
    const int t0 = blockIdx.x * 16 + w * 4;

    // preload 4 tokens into registers (register-blocked over tokens so the
    // 320 KB router_w is read once per 4 tokens, not once per token)
    float xr[4][16];
#pragma unroll
    for (int tt = 0; tt < 4; ++tt)
#pragma unroll
        for (int j = 0; j < 16; ++j)
            xr[tt][j] = hidden[(size_t)(t0 + tt) * HDIM + j * 64 + lane];

    for (int e = 0; e < NEZ; ++e) {
        float a0 = 0.f, a1 = 0.f, a2 = 0.f, a3 = 0.f;
        const float* r = rw + (size_t)e * HDIM;
#pragma unroll
        for (int j = 0; j < 16; ++j) {
            float rv = r[j * 64 + lane];
            a0 += xr[0][j] * rv; a1 += xr[1][j] * rv;
            a2 += xr[2][j] * rv; a3 += xr[3][j] * rv;
        }
#pragma unroll
        for (int off = 32; off > 0; off >>= 1) {
            a0 += __shfl_xor(a0, off);
            a1 += __shfl_xor(a1, off);
            a2 += __shfl_xor(a2, off);
            a3 += __shfl_xor(a3, off);
        }
        if (lane == 0) {
            sc[w * 4 + 0][e] = 1.f / (1.f + expf(-a0));
            sc[w * 4 + 1][e] = 1.f / (1.f + expf(-a1));
            sc[w * 4 + 2][e] = 1.f / (1.f + expf(-a2));
            sc[w * 4 + 3][e] = 1.f / (1.f + expf(-a3));
        }
    }
    __syncthreads();

    if (tid < 16) {
        const int t = blockIdx.x * 16 + tid;
        float b1 = -1e30f, b2 = -1e30f; int i1 = 0, i2 = 0;
        for (int e = 0; e < NEZ; ++e) {
            float b = sc[tid][e] + bias[e];
            if (b > b1) { b2 = b1; i2 = i1; b1 = b; i1 = e; }
            else if (b > b2) { b2 = b; i2 = e; }
        }
        float z = 0.f;
        int idx2[2] = { i1, i2 };
        for (int k = 0; k < 2; ++k) {
            int e = idx2[k];
            float wgt = sc[tid][e];
            float wr = 0.f;
            if (e >= NE) {
                z += wgt;                       // zero (identity) expert
            } else {
                int pos = atomicAdd(&cnt[e], 1);
                if (pos < CAPE) { slot_tok[e * CAPE + pos] = t * 2 + k; wr = wgt; }
                // pos >= CAPE => dropped, weight stays 0 (never happens here)
            }
            w_routed[t * 2 + k] = wr;
        }
        zc[t] = z;
    }
}

// ---------------- Gate/Up GEMM: G = silu(X Wg) * (X Wu), bf16 MFMA ----------------
// block tile 128(M) x 128(N), BK=64, 4 waves in 2x2, each wave 64x64 per matrix.
__global__ __launch_bounds__(256) void gateup_kernel(
    const float* __restrict__ hidden,
    const float* __restrict__ w_gate, const float* __restrict__ w_up,
    const int* __restrict__ cnt, const int* __restrict__ slot_tok,
    unsigned short* __restrict__ gbuf)
{
    const int e  = blockIdx.z;
    const int n0 = blockIdx.x * 128;
    const int m0 = blockIdx.y * 128;
    int cnt_e = cnt[e]; if (cnt_e > CAPE) cnt_e = CAPE;
    if (m0 >= cnt_e) return;

    __shared__ unsigned short As [128 * LDR];
    __shared__ unsigned short Bgs[128 * LDR];
    __shared__ unsigned short Bus[128 * LDR];

    const int tid = threadIdx.x;
    const int lane = tid & 63, wid = tid >> 6;
    const int wrow = (wid >> 1) * 64, wcol = (wid & 1) * 64;
    const int ml = lane & 15, quad = lane >> 4;

    floatx4 ag[4][4], au[4][4];
#pragma unroll
    for (int mt = 0; mt < 4; ++mt)
#pragma unroll
        for (int nt = 0; nt < 4; ++nt) {
            ag[mt][nt] = (floatx4){0.f, 0.f, 0.f, 0.f};
            au[mt][nt] = (floatx4){0.f, 0.f, 0.f, 0.f};
        }

    const float* wg_e = w_gate + (size_t)e * HDIM * IDIM;
    const float* wu_e = w_up   + (size_t)e * HDIM * IDIM;
    const int* st = slot_tok + e * CAPE;

    for (int kc = 0; kc < HDIM; kc += 64) {
        // stage A: 128 gathered token rows x 64 k, fp32 -> bf16
#pragma unroll
        for (int i = 0; i < 8; ++i) {
            int idx = tid + 256 * i;
            int row = idx >> 4, k4 = idx & 15;
            float4 v = make_float4(0.f, 0.f, 0.f, 0.f);
            int r = m0 + row;
            if (r < cnt_e) {
                int tok = st[r] >> 1;
                v = *(const float4*)(hidden + (size_t)tok * HDIM + kc + k4 * 4);
            }
            ushort4 p;
            p.x = f2bf(v.x); p.y = f2bf(v.y); p.z = f2bf(v.z); p.w = f2bf(v.w);
            *(ushort4*)&As[row * LDR + k4 * 4] = p;
        }
        // stage Bg/Bu transposed: global [k][n] -> LDS [n][k]
#pragma unroll
        for (int i = 0; i < 8; ++i) {
            int idx = tid + 256 * i;
            int k = idx >> 5, n4 = idx & 31;
            size_t goff = (size_t)(kc + k) * IDIM + n0 + n4 * 4;
            float4 g = *(const float4*)(wg_e + goff);
            float4 u = *(const float4*)(wu_e + goff);
            int nb = n4 * 4;
            Bgs[(nb + 0) * LDR + k] = f2bf(g.x);
            Bgs[(nb + 1) * LDR + k] = f2bf(g.y);
            Bgs[(nb + 2) * LDR + k] = f2bf(g.z);
            Bgs[(nb + 3) * LDR + k] = f2bf(g.w);
            Bus[(nb + 0) * LDR + k] = f2bf(u.x);
            Bus[(nb + 1) * LDR + k] = f2bf(u.y);
            Bus[(nb + 2) * LDR + k] = f2bf(u.z);
            Bus[(nb + 3) * LDR + k] = f2bf(u.w);
        }
        __syncthreads();

#pragma unroll
        for (int ks = 0; ks < 64; ks += 32) {
            bf16x8 a[4], bg[4], bu[4];
#pragma unroll
            for (int mt = 0; mt < 4; ++mt)
                a[mt] = *(const bf16x8*)&As[(wrow + mt * 16 + ml) * LDR + ks + quad * 8];
#pragma unroll
            for (int nt = 0; nt < 4; ++nt) {
                bg[nt] = *(const bf16x8*)&Bgs[(wcol + nt * 16 + ml) * LDR + ks + quad * 8];
                bu[nt] = *(const bf16x8*)&Bus[(wcol + nt * 16 + ml) * LDR + ks + quad * 8];
            }
#pragma unroll
            for (int mt = 0; mt < 4; ++mt)
#pragma unroll
                for (int nt = 0; nt < 4; ++nt) {
                    ag[mt][nt] = __builtin_amdgcn_mfma_f32_16x16x32_bf16(a[mt], bg[nt], ag[mt][nt], 0, 0, 0);
                    au[mt][nt] = __builtin_amdgcn_mfma_f32_16x16x32_bf16(a[mt], bu[nt], au[mt][nt], 0, 0, 0);
                }
        }
        __syncthreads();
    }

    // epilogue: g = silu(gate) * up -> bf16 gbuf[e][row][n]
#pragma unroll
    for (int mt = 0; mt < 4; ++mt) {
#pragma unroll
        for (int r4 = 0; r4 < 4; ++r4) {
            int r = m0 + wrow + mt * 16 + quad * 4 + r4;
            if (r < cnt_e) {
                unsigned short* grow = gbuf + (size_t)(e * CAPE + r) * IDIM + n0 + wcol;
#pragma unroll
                for (int nt = 0; nt < 4; ++nt) {
                    float g = ag[mt][nt][r4];
                    float u = au[mt][nt][r4];
                    float s = g / (1.f + __expf(-g));
                    grow[nt * 16 + ml] = f2bf(s * u);
                }
            }
        }
    }
}

// ---------------- Down GEMM: Y = G Wd, scatter rows to y2[t*2+k] ----------------
__global__ __launch_bounds__(256) void down_kernel(
    const unsigned short* __restrict__ gbuf, const float* __restrict__ w_down,
    const int* __restrict__ cnt, const int* __restrict__ slot_tok,
    unsigned short* __restrict__ y2)
{
    const int e  = blockIdx.z;
    const int n0 = blockIdx.x * 128;
    const int m0 = blockIdx.y * 128;
    int cnt_e = cnt[e]; if (cnt_e > CAPE) cnt_e = CAPE;
    if (m0 >= cnt_e) return;

    __shared__ unsigned short As[128 * LDR];
    __shared__ unsigned short Bs[128 * LDR];

    const int tid = threadIdx.x;
    const int lane = tid & 63, wid = tid >> 6;
    const int wrow = (wid >> 1) * 64, wcol = (wid & 1) * 64;
    const int ml = lane & 15, quad = lane >> 4;

    floatx4 acc[4][4];
#pragma unroll
    for (int mt = 0; mt < 4; ++mt)
#pragma unroll
        for (int nt = 0; nt < 4; ++nt)
            acc[mt][nt] = (floatx4){0.f, 0.f, 0.f, 0.f};

    const float* wd_e = w_down + (size_t)e * IDIM * HDIM;
    const int* st = slot_tok + e * CAPE;

    for (int kc = 0; kc < IDIM; kc += 64) {
        // stage A: 128 rows x 64 k of bf16 G (already bf16, straight copy)
#pragma unroll
        for (int i = 0; i < 4; ++i) {
            int idx = tid + 256 * i;            // 0..1023
            int row = idx >> 3, u8 = idx & 7;
            uint4 v = make_uint4(0u, 0u, 0u, 0u);
            int r = m0 + row;
            if (r < cnt_e)
                v = *(const uint4*)(gbuf + (size_t)(e * CAPE + r) * IDIM + kc + u8 * 8);
            *(uint4*)&As[row * LDR + u8 * 8] = v;
        }
        // stage B transposed: w_down [k][n] -> LDS [n][k]
#pragma unroll
        for (int i = 0; i < 8; ++i) {
            int idx = tid + 256 * i;
            int k = idx >> 5, n4 = idx & 31;
            float4 d = *(const float4*)(wd_e + (size_t)(kc + k) * HDIM + n0 + n4 * 4);
            int nb = n4 * 4;
            Bs[(nb + 0) * LDR + k] = f2bf(d.x);
            Bs[(nb + 1) * LDR + k] = f2bf(d.y);
            Bs[(nb + 2) * LDR + k] = f2bf(d.z);
            Bs[(nb + 3) * LDR + k] = f2bf(d.w);
        }
        __syncthreads();

#pragma unroll
        for (int ks = 0; ks < 64; ks += 32) {
            bf16x8 a[4], b[4];
#pragma unroll
            for (int mt = 0; mt < 4; ++mt)
                a[mt] = *(const bf16x8*)&As[(wrow + mt * 16 + ml) * LDR + ks + quad * 8];
#pragma unroll
            for (int nt = 0; nt < 4; ++nt)
                b[nt] = *(const bf16x8*)&Bs[(wcol + nt * 16 + ml) * LDR + ks + quad * 8];
#pragma unroll
            for (int mt = 0; mt < 4; ++mt)
#pragma unroll
                for (int nt = 0; nt < 4; ++nt)
                    acc[mt][nt] = __builtin_amdgcn_mfma_f32_16x16x32_bf16(a[mt], b[nt], acc[mt][nt], 0, 0, 0);
        }
        __syncthreads();
    }

    // epilogue: scatter rows to y2[slot][n] (slot = t*2+k), bf16
#pragma unroll
    for (int mt = 0; mt < 4; ++mt) {
#pragma unroll
        for (int r4 = 0; r4 < 4; ++r4) {
            int r = m0 + wrow + mt * 16 + quad * 4 + r4;
            if (r < cnt_e) {
                int slot = st[r];
                unsigned short* yrow = y2 + (size_t)slot * HDIM + n0 + wcol;
#pragma unroll
                for (int nt = 0; nt < 4; ++nt)
                    yrow[nt * 16 + ml] = f2bf(acc[mt][nt][r4]);
            }
        }
    }
}

// ---------------- Combine: out = 1.5*(zc*x + w0*y2[t,0] + w1*y2[t,1]) ----------------
__global__ __launch_bounds__(256) void combine_kernel(
    const float* __restrict__ hidden, const unsigned short* __restrict__ y2,
    const float* __restrict__ w_routed, const float* __restrict__ zc,
    float* __restrict__ out)
{
    int gid = blockIdx.x * 256 + threadIdx.x;
    int t = gid >> 8;
    int h = (gid & 255) * 4;
    float4 x = *(const float4*)(hidden + (size_t)t * HDIM + h);
    float w0 = w_routed[t * 2 + 0];
    float w1 = w_routed[t * 2 + 1];
    float z  = zc[t];
    ushort4 ya = *(const ushort4*)(y2 + (size_t)(t * 2 + 0) * HDIM + h);
    ushort4 yb = *(const ushort4*)(y2 + (size_t)(t * 2 + 1) * HDIM + h);
    float4 o;
    o.x = SCALEF * (z * x.x + w0 * bf2f(ya.x) + w1 * bf2f(yb.x));
    o.y = SCALEF * (z * x.y + w0 * bf2f(ya.y) + w1 * bf2f(yb.y));
    o.z = SCALEF * (z * x.z + w0 * bf2f(ya.z) + w1 * bf2f(yb.z));
    o.w = SCALEF * (z * x.w + w0 * bf2f(ya.w) + w1 * bf2f(yb.w));
    *(float4*)(out + (size_t)t * HDIM + h) = o;
}

// ---------------- workspace layout ----------------
#define OFF_CNT   0
#define OFF_SLOT  4096
#define OFF_WR    (OFF_SLOT + NE * CAPE * 4)          // 4096 + 81920
#define OFF_ZC    (OFF_WR + T_TOK * 2 * 4)            // + 32768
#define OFF_GBUF  (OFF_ZC + T_TOK * 4)                // + 16384 = 135168
#define OFF_Y2    (OFF_GBUF + (size_t)NE * CAPE * IDIM * 2)   // + 20971520
// total = OFF_Y2 + 8192*1024*2 = ~36.1 MB

extern "C" void kernel_launch(void* const* d_in, const int* in_sizes, int n_in,
                              void* d_out, int out_size, void* d_ws, size_t ws_size,
                              hipStream_t stream) {
    const float* hidden = (const float*)d_in[0];
    const float* rw     = (const float*)d_in[1];
    const float* bias   = (const float*)d_in[2];
    const float* w_gate = (const float*)d_in[3];
    const float* w_up   = (const float*)d_in[4];
    const float* w_down = (const float*)d_in[5];
    float* out = (float*)d_out;

    char* ws = (char*)d_ws;
    int*   cnt      = (int*)(ws + OFF_CNT);
    int*   slot_tok = (int*)(ws + OFF_SLOT);
    float* w_rt     = (float*)(ws + OFF_WR);
    float* zc       = (float*)(ws + OFF_ZC);
    unsigned short* gbuf = (unsigned short*)(ws + OFF_GBUF);
    unsigned short* y2   = (unsigned short*)(ws + OFF_Y2);

    hipMemsetAsync(cnt, 0, NE * sizeof(int), stream);

    router_kernel<<<T_TOK / 16, 256, 0, stream>>>(hidden, rw, bias, cnt, slot_tok, w_rt, zc);

    gateup_kernel<<<dim3(IDIM / 128, (CAPE + 127) / 128, NE), 256, 0, stream>>>(
        hidden, w_gate, w_up, cnt, slot_tok, gbuf);

    down_kernel<<<dim3(HDIM / 128, (CAPE + 127) / 128, NE), 256, 0, stream>>>(
        gbuf, w_down, cnt, slot_tok, y2);

    combine_kernel<<<(T_TOK * HDIM / 4) / 256, 256, 0, stream>>>(
        hidden, y2, w_rt, zc, out);
}

// Round 3
// 580.670 us; speedup vs baseline: 1.2139x; 1.2139x over previous
//
#include <hip/hip_runtime.h>
#include <hip/hip_bf16.h>
#include <stdint.h>

// LongcatMoe: T=4096, H=1024, I=512, E=64 routed + 16 zero, top-2, CAP=320, scale=1.5.
// R3: R2 structure with the down-epilogue indexing fix (sSlot is block-local,
// must be indexed by row-m0; R2 indexed it by global row -> OOB shared reads ->
// wild y2 scatters for experts with cnt>128).
// Tiles: gateup 128Mx32N, down 128Mx64N, BK=32, 1024 blocks each, 12KB LDS,
// launch_bounds(256,4), register prefetch pipeline, fragment-order LDS
// (ds_read_b128 at lane*16B, conflict-free).

#define T_TOK 4096
#define HDIM  1024
#define IDIM  512
#define NE    64
#define NEZ   80
#define CAPE  320
#define SCALEF 1.5f

typedef __attribute__((ext_vector_type(8))) short bf16x8;
typedef __attribute__((ext_vector_type(4))) float floatx4;

static __device__ __forceinline__ unsigned short f2bf(float f) {
    unsigned int x = __float_as_uint(f);
    x += 0x7fffu + ((x >> 16) & 1u);   // RNE
    return (unsigned short)(x >> 16);
}
static __device__ __forceinline__ float bf2f(unsigned short u) {
    return __uint_as_float(((unsigned int)u) << 16);
}

// ---------------- Router: fp32 logits, sigmoid, top-2, dispatch ----------------
__global__ __launch_bounds__(256) void router_kernel(
    const float* __restrict__ hidden, const float* __restrict__ rw,
    const float* __restrict__ bias, int* __restrict__ cnt,
    int* __restrict__ slot_tok, float* __restrict__ w_routed,
    float* __restrict__ zc)
{
    __shared__ float sc[16][NEZ];
    const int tid = threadIdx.x;
    const int w = tid >> 6, lane = tid & 63;
    const int t0 = blockIdx.x * 16 + w * 4;

    float xr[4][16];
#pragma unroll
    for (int tt = 0; tt < 4; ++tt)
#pragma unroll
        for (int j = 0; j < 16; ++j)
            xr[tt][j] = hidden[(size_t)(t0 + tt) * HDIM + j * 64 + lane];

    for (int e = 0; e < NEZ; ++e) {
        float a0 = 0.f, a1 = 0.f, a2 = 0.f, a3 = 0.f;
        const float* r = rw + (size_t)e * HDIM;
#pragma unroll
        for (int j = 0; j < 16; ++j) {
            float rv = r[j * 64 + lane];
            a0 += xr[0][j] * rv; a1 += xr[1][j] * rv;
            a2 += xr[2][j] * rv; a3 += xr[3][j] * rv;
        }
#pragma unroll
        for (int off = 32; off > 0; off >>= 1) {
            a0 += __shfl_xor(a0, off);
            a1 += __shfl_xor(a1, off);
            a2 += __shfl_xor(a2, off);
            a3 += __shfl_xor(a3, off);
        }
        if (lane == 0) {
            sc[w * 4 + 0][e] = 1.f / (1.f + expf(-a0));
            sc[w * 4 + 1][e] = 1.f / (1.f + expf(-a1));
            sc[w * 4 + 2][e] = 1.f / (1.f + expf(-a2));
            sc[w * 4 + 3][e] = 1.f / (1.f + expf(-a3));
        }
    }
    __syncthreads();

    if (tid < 16) {
        const int t = blockIdx.x * 16 + tid;
        float b1 = -1e30f, b2 = -1e30f; int i1 = 0, i2 = 0;
        for (int e = 0; e < NEZ; ++e) {
            float b = sc[tid][e] + bias[e];
            if (b > b1) { b2 = b1; i2 = i1; b1 = b; i1 = e; }
            else if (b > b2) { b2 = b; i2 = e; }
        }
        float z = 0.f;
        int idx2[2] = { i1, i2 };
        for (int k = 0; k < 2; ++k) {
            int e = idx2[k];
            float wgt = sc[tid][e];
            float wr = 0.f;
            if (e >= NE) {
                z += wgt;
            } else {
                int pos = atomicAdd(&cnt[e], 1);
                if (pos < CAPE) { slot_tok[e * CAPE + pos] = t * 2 + k; wr = wgt; }
            }
            w_routed[t * 2 + k] = wr;
        }
        zc[t] = z;
    }
}

// ---------------- Gate/Up GEMM: tile 128M x 32N, BK=32, frag-order LDS ----------------
// LDS (ushorts): A frag-chunks [8][512] at 0, Bg [2][512] at 4096, Bu [2][512] at 5120.
__global__ __launch_bounds__(256, 4) void gateup_kernel(
    const float* __restrict__ hidden,
    const float* __restrict__ w_gate, const float* __restrict__ w_up,
    const int* __restrict__ cnt, const int* __restrict__ slot_tok,
    unsigned short* __restrict__ gbuf)
{
    const int e  = blockIdx.z;
    const int n0 = blockIdx.x * 32;
    const int m0 = blockIdx.y * 128;
    int cnt_e = cnt[e]; if (cnt_e > CAPE) cnt_e = CAPE;
    if (m0 >= cnt_e) return;

    __shared__ unsigned short lds[6144];
    __shared__ int sTok[128];

    const int tid = threadIdx.x;
    const int lane = tid & 63, wid = tid >> 6;
    const int ml = lane & 15, quad = lane >> 4;

    if (tid < 128) {
        int r = m0 + tid;
        sTok[tid] = (r < cnt_e) ? (slot_tok[e * CAPE + r] >> 1) : 0;
    }
    __syncthreads();

    const int k4 = tid & 7;                    // A: k-group (4 floats)
    const int bn = tid & 31, bkq = tid >> 5;   // B: n col, k-group (4 floats)
    const size_t ebase = (size_t)e * HDIM * IDIM;
    const float* wgp = w_gate + ebase + (size_t)bkq * 4 * IDIM + n0 + bn;
    const float* wup = w_up   + ebase + (size_t)bkq * 4 * IDIM + n0 + bn;
    const int aoff_base = (k4 >> 1) * 128 + (k4 & 1) * 4;
    const int boff = (bn >> 4) * 512 + ((bkq >> 1) * 16 + (bn & 15)) * 8 + (bkq & 1) * 4;

    float4 aR[4];
    float  gR[4], uR[4];

    // prefetch kc=0
#pragma unroll
    for (int i = 0; i < 4; ++i) {
        int row = (tid >> 3) + 32 * i;
        aR[i] = *(const float4*)(hidden + (size_t)sTok[row] * HDIM + k4 * 4);
    }
#pragma unroll
    for (int j = 0; j < 4; ++j) { gR[j] = wgp[(size_t)j * IDIM]; uR[j] = wup[(size_t)j * IDIM]; }

    floatx4 ag[2][2], au[2][2];
#pragma unroll
    for (int mt = 0; mt < 2; ++mt)
#pragma unroll
        for (int nt = 0; nt < 2; ++nt) {
            ag[mt][nt] = (floatx4){0.f, 0.f, 0.f, 0.f};
            au[mt][nt] = (floatx4){0.f, 0.f, 0.f, 0.f};
        }

    for (int kc = 0; kc < HDIM; kc += 32) {
        // stage current regs -> LDS (fragment order)
#pragma unroll
        for (int i = 0; i < 4; ++i) {
            int row = (tid >> 3) + 32 * i;
            ushort4 p;
            p.x = f2bf(aR[i].x); p.y = f2bf(aR[i].y);
            p.z = f2bf(aR[i].z); p.w = f2bf(aR[i].w);
            *(ushort4*)&lds[(row >> 4) * 512 + (row & 15) * 8 + aoff_base] = p;
        }
        {
            ushort4 pg, pu;
            pg.x = f2bf(gR[0]); pg.y = f2bf(gR[1]); pg.z = f2bf(gR[2]); pg.w = f2bf(gR[3]);
            pu.x = f2bf(uR[0]); pu.y = f2bf(uR[1]); pu.z = f2bf(uR[2]); pu.w = f2bf(uR[3]);
            *(ushort4*)&lds[4096 + boff] = pg;
            *(ushort4*)&lds[5120 + boff] = pu;
        }
        __syncthreads();

        // issue next K-step's loads (stay in flight during MFMA)
        if (kc + 32 < HDIM) {
            int kn = kc + 32;
#pragma unroll
            for (int i = 0; i < 4; ++i) {
                int row = (tid >> 3) + 32 * i;
                aR[i] = *(const float4*)(hidden + (size_t)sTok[row] * HDIM + kn + k4 * 4);
            }
            const float* g = wgp + (size_t)kn * IDIM;
            const float* u = wup + (size_t)kn * IDIM;
#pragma unroll
            for (int j = 0; j < 4; ++j) { gR[j] = g[(size_t)j * IDIM]; uR[j] = u[(size_t)j * IDIM]; }
        }

        // compute: frag reads are lane*16B contiguous (conflict-free)
        bf16x8 a[2], bg[2], bu[2];
#pragma unroll
        for (int mt = 0; mt < 2; ++mt)
            a[mt] = *(const bf16x8*)&lds[(wid * 2 + mt) * 512 + lane * 8];
#pragma unroll
        for (int nt = 0; nt < 2; ++nt) {
            bg[nt] = *(const bf16x8*)&lds[4096 + nt * 512 + lane * 8];
            bu[nt] = *(const bf16x8*)&lds[5120 + nt * 512 + lane * 8];
        }
#pragma unroll
        for (int mt = 0; mt < 2; ++mt)
#pragma unroll
            for (int nt = 0; nt < 2; ++nt) {
                ag[mt][nt] = __builtin_amdgcn_mfma_f32_16x16x32_bf16(a[mt], bg[nt], ag[mt][nt], 0, 0, 0);
                au[mt][nt] = __builtin_amdgcn_mfma_f32_16x16x32_bf16(a[mt], bu[nt], au[mt][nt], 0, 0, 0);
            }
        __syncthreads();
    }

    // epilogue: g = silu(gate) * up -> bf16 gbuf[e][row][n]
#pragma unroll
    for (int mt = 0; mt < 2; ++mt) {
#pragma unroll
        for (int r4 = 0; r4 < 4; ++r4) {
            int row = m0 + wid * 32 + mt * 16 + quad * 4 + r4;
            if (row < cnt_e) {
                unsigned short* grow = gbuf + (size_t)(e * CAPE + row) * IDIM + n0;
#pragma unroll
                for (int nt = 0; nt < 2; ++nt) {
                    float g = ag[mt][nt][r4];
                    float u = au[mt][nt][r4];
                    float s = g / (1.f + __expf(-g));
                    grow[nt * 16 + ml] = f2bf(s * u);
                }
            }
        }
    }
}

// ---------------- Down GEMM: tile 128M x 64N, BK=32, frag-order LDS ----------------
// LDS (ushorts): A chunks [8][512] at 0, B chunks [4][512] at 4096.
__global__ __launch_bounds__(256, 4) void down_kernel(
    const unsigned short* __restrict__ gbuf, const float* __restrict__ w_down,
    const int* __restrict__ cnt, const int* __restrict__ slot_tok,
    unsigned short* __restrict__ y2)
{
    const int e  = blockIdx.z;
    const int n0 = blockIdx.x * 64;
    const int m0 = blockIdx.y * 128;
    int cnt_e = cnt[e]; if (cnt_e > CAPE) cnt_e = CAPE;
    if (m0 >= cnt_e) return;

    __shared__ unsigned short lds[6144];
    __shared__ int sSlot[128];

    const int tid = threadIdx.x;
    const int lane = tid & 63, wid = tid >> 6;
    const int ml = lane & 15, quad = lane >> 4;

    if (tid < 128) {
        int r = m0 + tid;
        sSlot[tid] = (r < cnt_e) ? slot_tok[e * CAPE + r] : 0;
    }
    __syncthreads();

    const int bn = tid & 63, bkq = tid >> 6;   // B: n col, k-group (8 floats)
    const float* wdp = w_down + (size_t)e * IDIM * HDIM + (size_t)bkq * 8 * HDIM + n0 + bn;
    const int boff = 4096 + (bn >> 4) * 512 + (bkq * 16 + (bn & 15)) * 8;

    uint4 aR[2];
    float bR[8];

    // prefetch kc=0 (rows >= cnt_e read clamped/poison; results discarded)
#pragma unroll
    for (int i = 0; i < 2; ++i) {
        int idx = tid + 256 * i;
        int row = idx >> 2, u8 = idx & 3;
        int r = m0 + row; if (r >= CAPE) r = CAPE - 1;
        aR[i] = *(const uint4*)(gbuf + (size_t)(e * CAPE + r) * IDIM + u8 * 8);
    }
#pragma unroll
    for (int j = 0; j < 8; ++j) bR[j] = wdp[(size_t)j * HDIM];

    floatx4 acc[4][2];
#pragma unroll
    for (int mt = 0; mt < 4; ++mt)
#pragma unroll
        for (int nt = 0; nt < 2; ++nt)
            acc[mt][nt] = (floatx4){0.f, 0.f, 0.f, 0.f};

    for (int kc = 0; kc < IDIM; kc += 32) {
        // stage
#pragma unroll
        for (int i = 0; i < 2; ++i) {
            int idx = tid + 256 * i;
            int row = idx >> 2, u8 = idx & 3;
            *(uint4*)&lds[(row >> 4) * 512 + (u8 * 16 + (row & 15)) * 8] = aR[i];
        }
        {
            union { unsigned short h[8]; uint4 v; } u;
#pragma unroll
            for (int j = 0; j < 8; ++j) u.h[j] = f2bf(bR[j]);
            *(uint4*)&lds[boff] = u.v;
        }
        __syncthreads();

        if (kc + 32 < IDIM) {
            int kn = kc + 32;
#pragma unroll
            for (int i = 0; i < 2; ++i) {
                int idx = tid + 256 * i;
                int row = idx >> 2, u8 = idx & 3;
                int r = m0 + row; if (r >= CAPE) r = CAPE - 1;
                aR[i] = *(const uint4*)(gbuf + (size_t)(e * CAPE + r) * IDIM + kn + u8 * 8);
            }
            const float* b = wdp + (size_t)kn * HDIM;
#pragma unroll
            for (int j = 0; j < 8; ++j) bR[j] = b[(size_t)j * HDIM];
        }

        bf16x8 a[4], b[2];
#pragma unroll
        for (int mt = 0; mt < 4; ++mt)
            a[mt] = *(const bf16x8*)&lds[((wid >> 1) * 4 + mt) * 512 + lane * 8];
#pragma unroll
        for (int nt = 0; nt < 2; ++nt)
            b[nt] = *(const bf16x8*)&lds[4096 + ((wid & 1) * 2 + nt) * 512 + lane * 8];
#pragma unroll
        for (int mt = 0; mt < 4; ++mt)
#pragma unroll
            for (int nt = 0; nt < 2; ++nt)
                acc[mt][nt] = __builtin_amdgcn_mfma_f32_16x16x32_bf16(a[mt], b[nt], acc[mt][nt], 0, 0, 0);
        __syncthreads();
    }

    // epilogue: scatter rows to y2[slot][n]. sSlot is BLOCK-LOCAL: index by lrow.
#pragma unroll
    for (int mt = 0; mt < 4; ++mt) {
#pragma unroll
        for (int r4 = 0; r4 < 4; ++r4) {
            int lrow = (wid >> 1) * 64 + mt * 16 + quad * 4 + r4;
            int row = m0 + lrow;
            if (row < cnt_e) {
                int slot = sSlot[lrow];
                unsigned short* yrow = y2 + (size_t)slot * HDIM + n0 + (wid & 1) * 32;
#pragma unroll
                for (int nt = 0; nt < 2; ++nt)
                    yrow[nt * 16 + ml] = f2bf(acc[mt][nt][r4]);
            }
        }
    }
}

// ---------------- Combine ----------------
__global__ __launch_bounds__(256) void combine_kernel(
    const float* __restrict__ hidden, const unsigned short* __restrict__ y2,
    const float* __restrict__ w_routed, const float* __restrict__ zc,
    float* __restrict__ out)
{
    int gid = blockIdx.x * 256 + threadIdx.x;
    int t = gid >> 8;
    int h = (gid & 255) * 4;
    float4 x = *(const float4*)(hidden + (size_t)t * HDIM + h);
    float w0 = w_routed[t * 2 + 0];
    float w1 = w_routed[t * 2 + 1];
    float z  = zc[t];
    ushort4 ya = *(const ushort4*)(y2 + (size_t)(t * 2 + 0) * HDIM + h);
    ushort4 yb = *(const ushort4*)(y2 + (size_t)(t * 2 + 1) * HDIM + h);
    float4 o;
    o.x = SCALEF * (z * x.x + w0 * bf2f(ya.x) + w1 * bf2f(yb.x));
    o.y = SCALEF * (z * x.y + w0 * bf2f(ya.y) + w1 * bf2f(yb.y));
    o.z = SCALEF * (z * x.z + w0 * bf2f(ya.z) + w1 * bf2f(yb.z));
    o.w = SCALEF * (z * x.w + w0 * bf2f(ya.w) + w1 * bf2f(yb.w));
    *(float4*)(out + (size_t)t * HDIM + h) = o;
}

// ---------------- workspace layout ----------------
#define OFF_CNT   0
#define OFF_SLOT  4096
#define OFF_WR    (OFF_SLOT + NE * CAPE * 4)
#define OFF_ZC    (OFF_WR + T_TOK * 2 * 4)
#define OFF_GBUF  (OFF_ZC + T_TOK * 4)
#define OFF_Y2    (OFF_GBUF + (size_t)NE * CAPE * IDIM * 2)

extern "C" void kernel_launch(void* const* d_in, const int* in_sizes, int n_in,
                              void* d_out, int out_size, void* d_ws, size_t ws_size,
                              hipStream_t stream) {
    const float* hidden = (const float*)d_in[0];
    const float* rw     = (const float*)d_in[1];
    const float* bias   = (const float*)d_in[2];
    const float* w_gate = (const float*)d_in[3];
    const float* w_up   = (const float*)d_in[4];
    const float* w_down = (const float*)d_in[5];
    float* out = (float*)d_out;

    char* ws = (char*)d_ws;
    int*   cnt      = (int*)(ws + OFF_CNT);
    int*   slot_tok = (int*)(ws + OFF_SLOT);
    float* w_rt     = (float*)(ws + OFF_WR);
    float* zc       = (float*)(ws + OFF_ZC);
    unsigned short* gbuf = (unsigned short*)(ws + OFF_GBUF);
    unsigned short* y2   = (unsigned short*)(ws + OFF_Y2);

    hipMemsetAsync(cnt, 0, NE * sizeof(int), stream);

    router_kernel<<<T_TOK / 16, 256, 0, stream>>>(hidden, rw, bias, cnt, slot_tok, w_rt, zc);

    gateup_kernel<<<dim3(IDIM / 32, (CAPE + 127) / 128, NE), 256, 0, stream>>>(
        hidden, w_gate, w_up, cnt, slot_tok, gbuf);

    down_kernel<<<dim3(HDIM / 64, (CAPE + 127) / 128, NE), 256, 0, stream>>>(
        gbuf, w_down, cnt, slot_tok, y2);

    combine_kernel<<<(T_TOK * HDIM / 4) / 256, 256, 0, stream>>>(
        hidden, y2, w_rt, zc, out);
}

// Round 4
// 539.858 us; speedup vs baseline: 1.3056x; 1.0756x over previous
//
#include <hip/hip_runtime.h>
#include <hip/hip_bf16.h>
#include <stdint.h>

// LongcatMoe: T=4096, H=1024, I=512, E=64 routed + 16 zero, top-2, CAP=320, scale=1.5.
// R4: DRAM page-locality fix. R3's 32N tile read 128 B per 2 KB weight row
// (stride 2 KB) -> page-activate-bound ~1.9 TB/s. Now 64Mx128N tiles: 512 B
// contiguous per row per block, 4 n-blocks of an expert launch adjacently and
// cover the full row. Frag-order LDS retained (k-strided dword global loads =
// 256 B/instr wave-contiguous; LDS writes contiguous b128; frag reads lane*16B
// conflict-free). Register prefetch pipeline retained.

#define T_TOK 4096
#define HDIM  1024
#define IDIM  512
#define NE    64
#define NEZ   80
#define CAPE  320
#define SCALEF 1.5f

typedef __attribute__((ext_vector_type(8))) short bf16x8;
typedef __attribute__((ext_vector_type(4))) float floatx4;

static __device__ __forceinline__ unsigned short f2bf(float f) {
    unsigned int x = __float_as_uint(f);
    x += 0x7fffu + ((x >> 16) & 1u);   // RNE
    return (unsigned short)(x >> 16);
}
static __device__ __forceinline__ float bf2f(unsigned short u) {
    return __uint_as_float(((unsigned int)u) << 16);
}
static __device__ __forceinline__ uint4 pack8(const float* f) {
    union { unsigned short h[8]; uint4 v; } u;
#pragma unroll
    for (int j = 0; j < 8; ++j) u.h[j] = f2bf(f[j]);
    return u.v;
}

// ---------------- Router: fp32 logits, sigmoid, top-2, dispatch ----------------
__global__ __launch_bounds__(256) void router_kernel(
    const float* __restrict__ hidden, const float* __restrict__ rw,
    const float* __restrict__ bias, int* __restrict__ cnt,
    int* __restrict__ slot_tok, float* __restrict__ w_routed,
    float* __restrict__ zc)
{
    __shared__ float sc[16][NEZ];
    const int tid = threadIdx.x;
    const int w = tid >> 6, lane = tid & 63;
    const int t0 = blockIdx.x * 16 + w * 4;

    float xr[4][16];
#pragma unroll
    for (int tt = 0; tt < 4; ++tt)
#pragma unroll
        for (int j = 0; j < 16; ++j)
            xr[tt][j] = hidden[(size_t)(t0 + tt) * HDIM + j * 64 + lane];

    for (int e = 0; e < NEZ; ++e) {
        float a0 = 0.f, a1 = 0.f, a2 = 0.f, a3 = 0.f;
        const float* r = rw + (size_t)e * HDIM;
#pragma unroll
        for (int j = 0; j < 16; ++j) {
            float rv = r[j * 64 + lane];
            a0 += xr[0][j] * rv; a1 += xr[1][j] * rv;
            a2 += xr[2][j] * rv; a3 += xr[3][j] * rv;
        }
#pragma unroll
        for (int off = 32; off > 0; off >>= 1) {
            a0 += __shfl_xor(a0, off);
            a1 += __shfl_xor(a1, off);
            a2 += __shfl_xor(a2, off);
            a3 += __shfl_xor(a3, off);
        }
        if (lane == 0) {
            sc[w * 4 + 0][e] = 1.f / (1.f + expf(-a0));
            sc[w * 4 + 1][e] = 1.f / (1.f + expf(-a1));
            sc[w * 4 + 2][e] = 1.f / (1.f + expf(-a2));
            sc[w * 4 + 3][e] = 1.f / (1.f + expf(-a3));
        }
    }
    __syncthreads();

    if (tid < 16) {
        const int t = blockIdx.x * 16 + tid;
        float b1 = -1e30f, b2 = -1e30f; int i1 = 0, i2 = 0;
        for (int e = 0; e < NEZ; ++e) {
            float b = sc[tid][e] + bias[e];
            if (b > b1) { b2 = b1; i2 = i1; b1 = b; i1 = e; }
            else if (b > b2) { b2 = b; i2 = e; }
        }
        float z = 0.f;
        int idx2[2] = { i1, i2 };
        for (int k = 0; k < 2; ++k) {
            int e = idx2[k];
            float wgt = sc[tid][e];
            float wr = 0.f;
            if (e >= NE) {
                z += wgt;
            } else {
                int pos = atomicAdd(&cnt[e], 1);
                if (pos < CAPE) { slot_tok[e * CAPE + pos] = t * 2 + k; wr = wgt; }
            }
            w_routed[t * 2 + k] = wr;
        }
        zc[t] = z;
    }
}

// ---------------- Gate/Up GEMM: tile 64M x 128N, BK=32 ----------------
// LDS (ushorts): A 4 chunks [4][512] at 0; Bg 8 chunks at 2048; Bu 8 at 6144.
// Chunk = 16 rows(cols) in frag order: lane l holds 8 values at l*16B.
#define GU_BG 2048
#define GU_BU 6144
__global__ __launch_bounds__(256, 2) void gateup_kernel(
    const float* __restrict__ hidden,
    const float* __restrict__ w_gate, const float* __restrict__ w_up,
    const int* __restrict__ cnt, const int* __restrict__ slot_tok,
    unsigned short* __restrict__ gbuf)
{
    const int e  = blockIdx.z;
    const int n0 = blockIdx.x * 128;
    const int m0 = blockIdx.y * 64;
    int cnt_e = cnt[e]; if (cnt_e > CAPE) cnt_e = CAPE;
    if (m0 >= cnt_e) return;

    __shared__ unsigned short lds[10240];  // 20 KB
    __shared__ int sTok[64];

    const int tid = threadIdx.x;
    const int lane = tid & 63, wid = tid >> 6;
    const int ml = lane & 15, quad = lane >> 4;
    const int wm = wid >> 1, wn = wid & 1;   // wave tile 32M x 64N

    if (tid < 64) {
        int r = m0 + tid;
        sTok[tid] = (r < cnt_e) ? (slot_tok[e * CAPE + r] >> 1) : 0;
    }
    __syncthreads();

    // A loader: idx = tid + 256p -> row = idx>>3 (0..63), k4 = idx&7 (float4 of k)
    const int arow0 = tid >> 3, ak4 = tid & 7;
    const int aoff0 = (arow0 >> 4) * 512 + ((ak4 >> 1) * 16 + (arow0 & 15)) * 8 + (ak4 & 1) * 4;
    const int arow1 = arow0 + 32;
    const int aoff1 = (arow1 >> 4) * 512 + ((ak4 >> 1) * 16 + (arow1 & 15)) * 8 + (ak4 & 1) * 4;
    // B loader: bn = tid&127 (n col), bk = tid>>7 (k half): k = bk*16 + jj
    const int bn = tid & 127, bk = tid >> 7;
    const int boff0 = (bn >> 4) * 512 + ((bk * 2) * 16 + (bn & 15)) * 8;  // jj=0..7
    const int boff1 = boff0 + 128;                                        // jj=8..15

    const size_t ebase = (size_t)e * HDIM * IDIM;
    const float* wg_p = w_gate + ebase + (size_t)(bk * 16) * IDIM + n0 + bn;
    const float* wu_p = w_up   + ebase + (size_t)(bk * 16) * IDIM + n0 + bn;
    const float* ha0 = hidden + (size_t)sTok[arow0] * HDIM + ak4 * 4;
    const float* ha1 = hidden + (size_t)sTok[arow1] * HDIM + ak4 * 4;

    float4 aR[2];
    float  gR[16], uR[16];

    // prefetch kc=0
    aR[0] = *(const float4*)ha0;
    aR[1] = *(const float4*)ha1;
#pragma unroll
    for (int jj = 0; jj < 16; ++jj) {
        gR[jj] = wg_p[(size_t)jj * IDIM];
        uR[jj] = wu_p[(size_t)jj * IDIM];
    }

    floatx4 ag[2][4], au[2][4];
#pragma unroll
    for (int mt = 0; mt < 2; ++mt)
#pragma unroll
        for (int nt = 0; nt < 4; ++nt) {
            ag[mt][nt] = (floatx4){0.f, 0.f, 0.f, 0.f};
            au[mt][nt] = (floatx4){0.f, 0.f, 0.f, 0.f};
        }

    for (int kc = 0; kc < HDIM; kc += 32) {
        // stage regs -> LDS (fragment order)
        {
            ushort4 p0, p1;
            p0.x = f2bf(aR[0].x); p0.y = f2bf(aR[0].y); p0.z = f2bf(aR[0].z); p0.w = f2bf(aR[0].w);
            p1.x = f2bf(aR[1].x); p1.y = f2bf(aR[1].y); p1.z = f2bf(aR[1].z); p1.w = f2bf(aR[1].w);
            *(ushort4*)&lds[aoff0] = p0;
            *(ushort4*)&lds[aoff1] = p1;
            *(uint4*)&lds[GU_BG + boff0] = pack8(gR);
            *(uint4*)&lds[GU_BG + boff1] = pack8(gR + 8);
            *(uint4*)&lds[GU_BU + boff0] = pack8(uR);
            *(uint4*)&lds[GU_BU + boff1] = pack8(uR + 8);
        }
        __syncthreads();

        // prefetch next K-step (stays in flight during MFMA)
        if (kc + 32 < HDIM) {
            ha0 += 32; ha1 += 32;
            wg_p += (size_t)32 * IDIM; wu_p += (size_t)32 * IDIM;
            aR[0] = *(const float4*)ha0;
            aR[1] = *(const float4*)ha1;
#pragma unroll
            for (int jj = 0; jj < 16; ++jj) {
                gR[jj] = wg_p[(size_t)jj * IDIM];
                uR[jj] = wu_p[(size_t)jj * IDIM];
            }
        }

        // fragments (lane*16B, conflict-free)
        bf16x8 a[2], bg[4], bu[4];
#pragma unroll
        for (int mt = 0; mt < 2; ++mt)
            a[mt] = *(const bf16x8*)&lds[(wm * 2 + mt) * 512 + lane * 8];
#pragma unroll
        for (int nt = 0; nt < 4; ++nt) {
            bg[nt] = *(const bf16x8*)&lds[GU_BG + (wn * 4 + nt) * 512 + lane * 8];
            bu[nt] = *(const bf16x8*)&lds[GU_BU + (wn * 4 + nt) * 512 + lane * 8];
        }
#pragma unroll
        for (int mt = 0; mt < 2; ++mt)
#pragma unroll
            for (int nt = 0; nt < 4; ++nt) {
                ag[mt][nt] = __builtin_amdgcn_mfma_f32_16x16x32_bf16(a[mt], bg[nt], ag[mt][nt], 0, 0, 0);
                au[mt][nt] = __builtin_amdgcn_mfma_f32_16x16x32_bf16(a[mt], bu[nt], au[mt][nt], 0, 0, 0);
            }
        __syncthreads();
    }

    // epilogue: g = silu(gate) * up -> bf16 gbuf[e][row][n]
#pragma unroll
    for (int mt = 0; mt < 2; ++mt) {
#pragma unroll
        for (int r4 = 0; r4 < 4; ++r4) {
            int gm = m0 + wm * 32 + mt * 16 + quad * 4 + r4;
            if (gm < cnt_e) {
                unsigned short* grow = gbuf + (size_t)(e * CAPE + gm) * IDIM + n0 + wn * 64;
#pragma unroll
                for (int nt = 0; nt < 4; ++nt) {
                    float g = ag[mt][nt][r4];
                    float u = au[mt][nt][r4];
                    float s = g / (1.f + __expf(-g));
                    grow[nt * 16 + ml] = f2bf(s * u);
                }
            }
        }
    }
}

// ---------------- Down GEMM: tile 64M x 128N, BK=32 ----------------
// LDS (ushorts): A 4 chunks at 0 (2048); B 8 chunks at 2048 (4096).
#define DN_B 2048
__global__ __launch_bounds__(256, 4) void down_kernel(
    const unsigned short* __restrict__ gbuf, const float* __restrict__ w_down,
    const int* __restrict__ cnt, const int* __restrict__ slot_tok,
    unsigned short* __restrict__ y2)
{
    const int e  = blockIdx.z;
    const int n0 = blockIdx.x * 128;
    const int m0 = blockIdx.y * 64;
    int cnt_e = cnt[e]; if (cnt_e > CAPE) cnt_e = CAPE;
    if (m0 >= cnt_e) return;

    __shared__ unsigned short lds[6144];  // 12 KB
    __shared__ int sSlot[64];

    const int tid = threadIdx.x;
    const int lane = tid & 63, wid = tid >> 6;
    const int ml = lane & 15, quad = lane >> 4;
    const int wm = wid >> 1, wn = wid & 1;   // wave tile 32M x 64N

    if (tid < 64) {
        int r = m0 + tid;
        sSlot[tid] = (r < cnt_e) ? slot_tok[e * CAPE + r] : 0;
    }
    __syncthreads();

    // A loader: row = tid>>2 (0..63), u8 = tid&3 (8 bf16 of k)
    const int arow = tid >> 2, au8 = tid & 3;
    const int aoff = (arow >> 4) * 512 + (au8 * 16 + (arow & 15)) * 8;
    const unsigned short* gp = gbuf + (size_t)(e * CAPE + m0 + arow) * IDIM + au8 * 8;
    // B loader: bn = tid&127, bk = tid>>7: k = bk*16 + jj
    const int bn = tid & 127, bk = tid >> 7;
    const int boff0 = (bn >> 4) * 512 + ((bk * 2) * 16 + (bn & 15)) * 8;
    const int boff1 = boff0 + 128;
    const float* wd_p = w_down + (size_t)e * IDIM * HDIM + (size_t)(bk * 16) * HDIM + n0 + bn;

    uint4 aR;
    float bR[16];

    aR = *(const uint4*)gp;
#pragma unroll
    for (int jj = 0; jj < 16; ++jj) bR[jj] = wd_p[(size_t)jj * HDIM];

    floatx4 acc[2][4];
#pragma unroll
    for (int mt = 0; mt < 2; ++mt)
#pragma unroll
        for (int nt = 0; nt < 4; ++nt)
            acc[mt][nt] = (floatx4){0.f, 0.f, 0.f, 0.f};

    for (int kc = 0; kc < IDIM; kc += 32) {
        *(uint4*)&lds[aoff] = aR;
        *(uint4*)&lds[DN_B + boff0] = pack8(bR);
        *(uint4*)&lds[DN_B + boff1] = pack8(bR + 8);
        __syncthreads();

        if (kc + 32 < IDIM) {
            gp += 32;
            wd_p += (size_t)32 * HDIM;
            aR = *(const uint4*)gp;
#pragma unroll
            for (int jj = 0; jj < 16; ++jj) bR[jj] = wd_p[(size_t)jj * HDIM];
        }

        bf16x8 a[2], b[4];
#pragma unroll
        for (int mt = 0; mt < 2; ++mt)
            a[mt] = *(const bf16x8*)&lds[(wm * 2 + mt) * 512 + lane * 8];
#pragma unroll
        for (int nt = 0; nt < 4; ++nt)
            b[nt] = *(const bf16x8*)&lds[DN_B + (wn * 4 + nt) * 512 + lane * 8];
#pragma unroll
        for (int mt = 0; mt < 2; ++mt)
#pragma unroll
            for (int nt = 0; nt < 4; ++nt)
                acc[mt][nt] = __builtin_amdgcn_mfma_f32_16x16x32_bf16(a[mt], b[nt], acc[mt][nt], 0, 0, 0);
        __syncthreads();
    }

    // epilogue: scatter rows to y2[slot][n]; sSlot indexed by LOCAL row
#pragma unroll
    for (int mt = 0; mt < 2; ++mt) {
#pragma unroll
        for (int r4 = 0; r4 < 4; ++r4) {
            int lrow = wm * 32 + mt * 16 + quad * 4 + r4;
            if (m0 + lrow < cnt_e) {
                int slot = sSlot[lrow];
                unsigned short* yrow = y2 + (size_t)slot * HDIM + n0 + wn * 64;
#pragma unroll
                for (int nt = 0; nt < 4; ++nt)
                    yrow[nt * 16 + ml] = f2bf(acc[mt][nt][r4]);
            }
        }
    }
}

// ---------------- Combine ----------------
__global__ __launch_bounds__(256) void combine_kernel(
    const float* __restrict__ hidden, const unsigned short* __restrict__ y2,
    const float* __restrict__ w_routed, const float* __restrict__ zc,
    float* __restrict__ out)
{
    int gid = blockIdx.x * 256 + threadIdx.x;
    int t = gid >> 8;
    int h = (gid & 255) * 4;
    float4 x = *(const float4*)(hidden + (size_t)t * HDIM + h);
    float w0 = w_routed[t * 2 + 0];
    float w1 = w_routed[t * 2 + 1];
    float z  = zc[t];
    ushort4 ya = *(const ushort4*)(y2 + (size_t)(t * 2 + 0) * HDIM + h);
    ushort4 yb = *(const ushort4*)(y2 + (size_t)(t * 2 + 1) * HDIM + h);
    float4 o;
    o.x = SCALEF * (z * x.x + w0 * bf2f(ya.x) + w1 * bf2f(yb.x));
    o.y = SCALEF * (z * x.y + w0 * bf2f(ya.y) + w1 * bf2f(yb.y));
    o.z = SCALEF * (z * x.z + w0 * bf2f(ya.z) + w1 * bf2f(yb.z));
    o.w = SCALEF * (z * x.w + w0 * bf2f(ya.w) + w1 * bf2f(yb.w));
    *(float4*)(out + (size_t)t * HDIM + h) = o;
}

// ---------------- workspace layout ----------------
#define OFF_CNT   0
#define OFF_SLOT  4096
#define OFF_WR    (OFF_SLOT + NE * CAPE * 4)
#define OFF_ZC    (OFF_WR + T_TOK * 2 * 4)
#define OFF_GBUF  (OFF_ZC + T_TOK * 4)
#define OFF_Y2    (OFF_GBUF + (size_t)NE * CAPE * IDIM * 2)

extern "C" void kernel_launch(void* const* d_in, const int* in_sizes, int n_in,
                              void* d_out, int out_size, void* d_ws, size_t ws_size,
                              hipStream_t stream) {
    const float* hidden = (const float*)d_in[0];
    const float* rw     = (const float*)d_in[1];
    const float* bias   = (const float*)d_in[2];
    const float* w_gate = (const float*)d_in[3];
    const float* w_up   = (const float*)d_in[4];
    const float* w_down = (const float*)d_in[5];
    float* out = (float*)d_out;

    char* ws = (char*)d_ws;
    int*   cnt      = (int*)(ws + OFF_CNT);
    int*   slot_tok = (int*)(ws + OFF_SLOT);
    float* w_rt     = (float*)(ws + OFF_WR);
    float* zc       = (float*)(ws + OFF_ZC);
    unsigned short* gbuf = (unsigned short*)(ws + OFF_GBUF);
    unsigned short* y2   = (unsigned short*)(ws + OFF_Y2);

    hipMemsetAsync(cnt, 0, NE * sizeof(int), stream);

    router_kernel<<<T_TOK / 16, 256, 0, stream>>>(hidden, rw, bias, cnt, slot_tok, w_rt, zc);

    gateup_kernel<<<dim3(IDIM / 128, (CAPE + 63) / 64, NE), 256, 0, stream>>>(
        hidden, w_gate, w_up, cnt, slot_tok, gbuf);

    down_kernel<<<dim3(HDIM / 128, (CAPE + 63) / 64, NE), 256, 0, stream>>>(
        gbuf, w_down, cnt, slot_tok, y2);

    combine_kernel<<<(T_TOK * HDIM / 4) / 256, 256, 0, stream>>>(
        hidden, y2, w_rt, zc, out);
}